// Round 1
// baseline (126.673 us; speedup 1.0000x reference)
//
#include <hip/hip_runtime.h>
#include <hip/hip_bf16.h>

// VariableSelectionNetwork fused kernel.
//
// Key observation: in the reference, the sel-GRN fc1/fc2 outputs and the big
// nvh,vho einsum result are DEAD (never used by the returned value). The live
// computation is:
//   weights = softmax(LN(GLU(x @ sel_gate_w + b) + x))            [N,32]
//   y[n,v,o] = sigmoid(x*gw+gb)*(x*gw'+gb') + (x*sw+sb)           [N,32,256]
//   proc     = LN_o(y) * ln_g + ln_b
//   out[n,o] = sum_v weights[n,v] * proc[n,v,o]                   [N,256]

#define VDIM 32
#define ODIM 256
#define RPB  16          // rows per block
#define TPB  512         // threads per block (8 waves)
#define RPW  2           // rows per wave (RPB / 8 waves)

__device__ __forceinline__ float fast_sigmoid(float g) {
    // 1 / (1 + exp(-g)); exp overflow -> inf -> rcp -> 0, correct limit.
    return __builtin_amdgcn_rcpf(1.0f + __expf(-g));
}

__global__ void __launch_bounds__(TPB) vsn_fused(
    const float* __restrict__ x,     // [N,32]
    const float* __restrict__ sgw,   // [32,64] sel_gate_w
    const float* __restrict__ sgb,   // [64]
    const float* __restrict__ slg,   // [32]
    const float* __restrict__ slb,   // [32]
    const float* __restrict__ vgw,   // [32,512] var_gate_w
    const float* __restrict__ vgb,   // [32,512]
    const float* __restrict__ vsw,   // [32,256] var_skip_w
    const float* __restrict__ vsb,   // [32,256]
    const float* __restrict__ vlg,   // [32,256] var_ln_g
    const float* __restrict__ vlb,   // [32,256]
    float* __restrict__ out)         // [N,256]
{
    __shared__ float x_s[RPB][VDIM];
    __shared__ float g_s[RPB][2 * VDIM];
    __shared__ float w_s[RPB][VDIM];

    const int tid  = threadIdx.x;
    const int row0 = blockIdx.x * RPB;

    // ---- load x rows (16*32 = 512 floats) ----
    {
        const int i = tid;  // TPB == 512 == RPB*VDIM
        ((float*)x_s)[i] = x[row0 * VDIM + i];
    }
    __syncthreads();

    // ---- Phase A1: g = x @ sel_gate_w + sel_gate_b  (16 rows x 64 cols) ----
    #pragma unroll
    for (int i = tid; i < RPB * 64; i += TPB) {
        const int r = i >> 6, j = i & 63;
        float acc = sgb[j];
        #pragma unroll
        for (int v = 0; v < VDIM; ++v)
            acc = fmaf(x_s[r][v], sgw[v * 64 + j], acc);
        g_s[r][j] = acc;
    }
    __syncthreads();

    // ---- Phase A2: GLU -> +x -> LN(32) -> softmax(32) -> weights ----
    {
        const int i = tid;  // 512 tasks == TPB
        const int r = i >> 5, v = i & 31;
        const float gate = g_s[r][v];
        const float val  = g_s[r][VDIM + v];
        const float y    = fast_sigmoid(gate) * val + x_s[r][v];
        float s1 = y, s2 = y * y;
        #pragma unroll
        for (int m = 1; m < 32; m <<= 1) {
            s1 += __shfl_xor(s1, m, 64);
            s2 += __shfl_xor(s2, m, 64);
        }
        const float mean = s1 * (1.0f / VDIM);
        const float var  = s2 * (1.0f / VDIM) - mean * mean;
        const float rs   = __builtin_amdgcn_rsqf(var + 1e-5f);
        const float sel  = slg[v] * ((y - mean) * rs) + slb[v];
        float mx = sel;
        #pragma unroll
        for (int m = 1; m < 32; m <<= 1)
            mx = fmaxf(mx, __shfl_xor(mx, m, 64));
        const float e = __expf(sel - mx);
        float se = e;
        #pragma unroll
        for (int m = 1; m < 32; m <<= 1)
            se += __shfl_xor(se, m, 64);
        w_s[r][v] = e * __builtin_amdgcn_rcpf(se);
    }
    __syncthreads();

    // ---- Phase B: per-variable GLU+skip -> LN(256) -> weighted sum ----
    const int wave = tid >> 6;        // 0..7
    const int lane = tid & 63;
    const int o0   = lane << 2;       // o-quad base: lane l owns o in [4l,4l+3]
    const int r0   = wave * RPW;

    float acc[RPW][4];
    #pragma unroll
    for (int r = 0; r < RPW; ++r) {
        acc[r][0] = 0.0f; acc[r][1] = 0.0f; acc[r][2] = 0.0f; acc[r][3] = 0.0f;
    }

    for (int v = 0; v < VDIM; ++v) {
        const float4 ga  = *(const float4*)(vgw + v * 512 + o0);        // gate w
        const float4 va  = *(const float4*)(vgw + v * 512 + 256 + o0);  // value w
        const float4 gab = *(const float4*)(vgb + v * 512 + o0);        // gate b
        const float4 vab = *(const float4*)(vgb + v * 512 + 256 + o0);  // value b
        const float4 sw4 = *(const float4*)(vsw + v * 256 + o0);        // skip w
        const float4 sb4 = *(const float4*)(vsb + v * 256 + o0);        // skip b
        const float4 lg4 = *(const float4*)(vlg + v * 256 + o0);        // ln g
        const float4 lb4 = *(const float4*)(vlb + v * 256 + o0);        // ln b

        #pragma unroll
        for (int rr = 0; rr < RPW; ++rr) {
            const float xv = x_s[r0 + rr][v];

            const float y0 = fast_sigmoid(fmaf(xv, ga.x, gab.x)) * fmaf(xv, va.x, vab.x) + fmaf(xv, sw4.x, sb4.x);
            const float y1 = fast_sigmoid(fmaf(xv, ga.y, gab.y)) * fmaf(xv, va.y, vab.y) + fmaf(xv, sw4.y, sb4.y);
            const float y2 = fast_sigmoid(fmaf(xv, ga.z, gab.z)) * fmaf(xv, va.z, vab.z) + fmaf(xv, sw4.z, sb4.z);
            const float y3 = fast_sigmoid(fmaf(xv, ga.w, gab.w)) * fmaf(xv, va.w, vab.w) + fmaf(xv, sw4.w, sb4.w);

            float s1 = (y0 + y1) + (y2 + y3);
            float s2 = fmaf(y0, y0, fmaf(y1, y1, fmaf(y2, y2, y3 * y3)));
            #pragma unroll
            for (int m = 1; m < 64; m <<= 1) {
                s1 += __shfl_xor(s1, m, 64);
                s2 += __shfl_xor(s2, m, 64);
            }
            const float mean = s1 * (1.0f / ODIM);
            const float var  = s2 * (1.0f / ODIM) - mean * mean;
            const float rs   = __builtin_amdgcn_rsqf(var + 1e-5f);
            const float wv   = w_s[r0 + rr][v];
            const float wrs  = wv * rs;   // w * rsqrt folded together
            // acc += w*(lg*((y-m)*rs) + lb) == lg*((y-m)*w*rs) + w*lb
            acc[rr][0] = fmaf(lg4.x, (y0 - mean) * wrs, fmaf(wv, lb4.x, acc[rr][0]));
            acc[rr][1] = fmaf(lg4.y, (y1 - mean) * wrs, fmaf(wv, lb4.y, acc[rr][1]));
            acc[rr][2] = fmaf(lg4.z, (y2 - mean) * wrs, fmaf(wv, lb4.z, acc[rr][2]));
            acc[rr][3] = fmaf(lg4.w, (y3 - mean) * wrs, fmaf(wv, lb4.w, acc[rr][3]));
        }
    }

    #pragma unroll
    for (int rr = 0; rr < RPW; ++rr) {
        float4 o4 = make_float4(acc[rr][0], acc[rr][1], acc[rr][2], acc[rr][3]);
        *(float4*)(out + (size_t)(row0 + r0 + rr) * ODIM + o0) = o4;
    }
}

extern "C" void kernel_launch(void* const* d_in, const int* in_sizes, int n_in,
                              void* d_out, int out_size, void* d_ws, size_t ws_size,
                              hipStream_t stream) {
    // setup_inputs order:
    // 0 x | 1 sel_fc1_w | 2 sel_fc1_b | 3 sel_fc2_w | 4 sel_fc2_b (dead)
    // 5 sel_gate_w | 6 sel_gate_b | 7 sel_ln_g | 8 sel_ln_b
    // 9 var_fc1_w | 10 var_fc1_b | 11 var_fc2_w | 12 var_fc2_b (dead)
    // 13 var_gate_w | 14 var_gate_b | 15 var_skip_w | 16 var_skip_b
    // 17 var_ln_g | 18 var_ln_b
    const float* x   = (const float*)d_in[0];
    const float* sgw = (const float*)d_in[5];
    const float* sgb = (const float*)d_in[6];
    const float* slg = (const float*)d_in[7];
    const float* slb = (const float*)d_in[8];
    const float* vgw = (const float*)d_in[13];
    const float* vgb = (const float*)d_in[14];
    const float* vsw = (const float*)d_in[15];
    const float* vsb = (const float*)d_in[16];
    const float* vlg = (const float*)d_in[17];
    const float* vlb = (const float*)d_in[18];
    float* out = (float*)d_out;

    const int N = in_sizes[0] / VDIM;      // 4096 rows
    const int grid = N / RPB;              // 256 blocks

    vsn_fused<<<grid, TPB, 0, stream>>>(x, sgw, sgb, slg, slb,
                                        vgw, vgb, vsw, vsb, vlg, vlb, out);
}